// Round 1
// 240.160 us; speedup vs baseline: 1.0336x; 1.0336x over previous
//
#include <hip/hip_runtime.h>

// PatchEmbedding2 on MI355X — round 8.
// r7 diagnosis: gemm occupancy 10.4% — 378 blocks (128x128 tiles) on 256 CUs
// with 64KB LDS (2 blocks/CU cap) -> 74% load-balance efficiency, latency-bound
// (MfmaUtil 18.6%, HBM 30%, bank conflicts 0: no pipe saturated).
// Fix: BM=128 BN=64 BK=64 dbuf -> 48KB LDS, 3 blocks/CU, 756 blocks = 252 CUs
// x 3 (98% balance), 12 waves/CU. Bijective XCD-chunked swizzle (756%8!=0) with
// N-fastest work order: the 12 blocks sharing one 768KB A-panel stay on one
// XCD's L2. Swizzled 16B-chunk staging (conflict-free, r7 counter=0) unchanged.
// prep/gather: unchanged from r7 (r3/r4-verified).

typedef __attribute__((ext_vector_type(8))) short bf16x8;
typedef __attribute__((ext_vector_type(4))) float f32x4;

#define K_DIM 3072
#define N_DIM 768

__device__ __forceinline__ unsigned short f2bf(float f) {
  unsigned int u = __float_as_uint(f);
  u += 0x7fffu + ((u >> 16) & 1u);   // RNE
  return (unsigned short)(u >> 16);
}

__device__ __forceinline__ void gload16(const void* g, void* l) {
  __builtin_amdgcn_global_load_lds(
      (const __attribute__((address_space(1))) void*)g,
      (__attribute__((address_space(3))) void*)l, 16, 0, 0);
}

// ---------------- prep: wconv (row-major) + layout ----------------
__global__ __launch_bounds__(1024)
void prep_kernel(const float* __restrict__ W, unsigned short* __restrict__ Wb, int w4,
                 const float* __restrict__ iw, int P,
                 int* __restrict__ tokBase, int* __restrict__ tokMask, int NB_W) {
  int bid = blockIdx.x;
  int tid = threadIdx.x;
  if (bid < NB_W) {
    int idx = bid * 1024 + tid;
    if (idx < w4) {
      float4 f = *(const float4*)(W + (size_t)idx * 4);
      ushort4 o;
      o.x = f2bf(f.x); o.y = f2bf(f.y); o.z = f2bf(f.z); o.w = f2bf(f.w);
      *(ushort4*)(Wb + (size_t)idx * 4) = o;
    }
    return;
  }
  // ---- layout (single block, r2-verified) ----
  __shared__ double s_wsum[16];
  __shared__ double s_avg;
  __shared__ int s_cnt[1024];
  float v = (tid < P) ? iw[tid] : 0.0f;
  double d = (double)v;
#pragma unroll
  for (int off = 32; off > 0; off >>= 1) d += __shfl_down(d, off, 64);
  if ((tid & 63) == 0) s_wsum[tid >> 6] = d;
  __syncthreads();
  if (tid == 0) {
    double s = 0.0;
    for (int i = 0; i < 16; ++i) s += s_wsum[i];
    s_avg = s / (double)P;
  }
  __syncthreads();
  int cnt = 0, sz = 32;
  if (tid < P) {
    double val = 32.0 * pow(s_avg / (double)v, 0.05);
    if (val > 32.0) val = 32.0;
    sz = (val >= 24.0) ? 32 : (val >= 12.0) ? 16 : (val >= 6.0) ? 8 : 4;
    cnt = (sz < 32) ? (32 / sz) : 1;
  }
  s_cnt[tid] = cnt;
  __syncthreads();
  for (int dl = 1; dl < 1024; dl <<= 1) {
    int add = (tid >= dl) ? s_cnt[tid - dl] : 0;
    __syncthreads();
    s_cnt[tid] += add;
    __syncthreads();
  }
  if (tid < P) {
    int off = s_cnt[tid] - cnt;
    int ini_col = (tid * 32) & 1023;
    int ini_row = (tid * 32 * 32) >> 10;
    if (sz == 32) {
      tokBase[off] = ini_row * 1024 + ini_col;
      tokMask[off] = 31;
    } else {
      int ns = 32 / sz;
      for (int j = 0; j < ns; ++j) {
        int r = ini_row + (j * sz) / ns;
        int c = ini_col + ((j * sz) & 31);
        tokBase[off + j] = r * 1024 + c;
        tokMask[off + j] = sz - 1;
      }
    }
  }
}

// ---------------- gather: row-major Ab, one block per A row (r3/r4-verified) ---
__global__ __launch_bounds__(256)
void gather_kernel(const float* __restrict__ x,
                   const int* __restrict__ tokBase,
                   const int* __restrict__ tokMask,
                   unsigned short* __restrict__ Ab) {
  int t = blockIdx.x;
  int b = blockIdx.y;
  int T = gridDim.x;
  int m = b * T + t;
  int base = tokBase[t];
  int mask = tokMask[t];
  int sh = __popc(mask);
  const float* xb = x + (size_t)b * 3145728 + (size_t)base;
  unsigned short* arow = Ab + (size_t)m * K_DIM;
#pragma unroll
  for (int it = 0; it < 3; ++it) {
    int g = it * 256 + threadIdx.x;
    int p = g * 4;
    int c = p >> 10;
    int f = p & 1023;
    int h = (f >> sh) & mask;
    int w = f & mask;
    float4 fv = *(const float4*)(xb + (size_t)c * 1048576 + h * 1024 + w);
    ushort4 o;
    o.x = f2bf(fv.x); o.y = f2bf(fv.y); o.z = f2bf(fv.z); o.w = f2bf(fv.w);
    *(ushort4*)(arow + p) = o;
  }
}

// ---------------- gemm: 128x64 x BK64, dbuf LDS, 1 barrier/iter, 3 blk/CU ----
__global__ __launch_bounds__(256, 3)
void gemm_kernel(const unsigned short* __restrict__ A, const unsigned short* __restrict__ Wb,
                 const float* __restrict__ bias, float* __restrict__ out, int Mtot) {
  // per buf: A 128x64 halves (16 KB) at 0, B 64x64 halves (8 KB) at 8192.
  // row = 128 B = 8 chunks of 16 B; chunk c of row r stored at slot c^(r&7)
  // (swizzle applied in the GLOBAL src addr; gll LDS dst is linear lane*16).
  __shared__ unsigned short lds[2][12288];   // 48 KB total
  int tid = threadIdx.x;
  int lane = tid & 63;
  int wave = tid >> 6;
  int wr = wave >> 1, wc = wave & 1;         // wave tile: 64 rows x 32 cols

  // bijective XCD-chunked swizzle (m204): consecutive work ids (N-fastest,
  // sharing an A-panel) land on one XCD.
  int lin = blockIdx.x;
  int nwg = gridDim.x;                       // 756
  int q8 = nwg >> 3, r8 = nwg & 7;           // 94, 4
  int xcd = lin & 7, slot = lin >> 3;
  int wg = (xcd < r8) ? xcd * (q8 + 1) + slot
                      : r8 * (q8 + 1) + (xcd - r8) * q8 + slot;
  int mBase = (wg / 12) * 128;
  int nBase = (wg % 12) * 64;

  f32x4 acc[4][2] = {};

  // staging per buf: A = 4 gll insts/wave (rows wave*32+inst*8+(lane>>3)),
  // B = 2 gll insts/wave (rows wave*16+inst*8+(lane>>3)). Source chunk is
  // pre-swizzled: (lane&7)^(lane>>3)  (row&7 == lane>>3 for every inst).
  int lrow = lane >> 3;
  int schunk = (lane & 7) ^ lrow;
  const unsigned short* Ag = A + (size_t)(mBase + wave * 32 + lrow) * K_DIM + schunk * 8;
  const unsigned short* Bg = Wb + (size_t)(nBase + wave * 16 + lrow) * K_DIM + schunk * 8;
  unsigned short* Adst0 = &lds[0][(wave * 32) * 64] + lane * 8;          // +inst*512
  unsigned short* Bdst0 = &lds[0][8192 + (wave * 16) * 64] + lane * 8;   // +inst*512

#define STAGE(BUF, KOFF)                                                    \
  {                                                                         \
    _Pragma("unroll")                                                       \
    for (int inst = 0; inst < 4; ++inst)                                    \
      gload16(Ag + (size_t)(inst * 8) * K_DIM + (KOFF),                     \
              Adst0 + (size_t)(BUF) * 12288 + inst * 512);                  \
    _Pragma("unroll")                                                       \
    for (int inst = 0; inst < 2; ++inst)                                    \
      gload16(Bg + (size_t)(inst * 8) * K_DIM + (KOFF),                     \
              Bdst0 + (size_t)(BUF) * 12288 + inst * 512);                  \
  }

  int rr = lane & 15, q = lane >> 4;
  int r7 = rr & 7;

#define COMPUTE(BUF)                                                        \
  {                                                                         \
    const unsigned short* A_ = &lds[BUF][0];                                \
    const unsigned short* B_ = &lds[BUF][8192];                             \
    _Pragma("unroll")                                                       \
    for (int kh = 0; kh < 2; ++kh) {                                        \
      bf16x8 aF[4], bF[2];                                                  \
      _Pragma("unroll")                                                     \
      for (int i = 0; i < 4; ++i)                                           \
        aF[i] = *(const bf16x8*)&A_[(wr * 64 + i * 16 + rr) * 64 +          \
                                    ((kh * 4 + q) ^ r7) * 8];               \
      _Pragma("unroll")                                                     \
      for (int j = 0; j < 2; ++j)                                           \
        bF[j] = *(const bf16x8*)&B_[(wc * 32 + j * 16 + rr) * 64 +          \
                                    ((kh * 4 + q) ^ r7) * 8];               \
      _Pragma("unroll")                                                     \
      for (int i = 0; i < 4; ++i)                                           \
        _Pragma("unroll")                                                   \
        for (int j = 0; j < 2; ++j)                                         \
          acc[i][j] = __builtin_amdgcn_mfma_f32_16x16x32_bf16(aF[i], bF[j], \
                                                              acc[i][j], 0, 0, 0); \
    }                                                                       \
  }

  STAGE(0, 0)
  __syncthreads();                 // buf0 ready
  int buf = 0;
  for (int k0 = 0; k0 < K_DIM; k0 += 64) {
    if (k0 + 64 < K_DIM) {
      if (buf == 0) STAGE(1, k0 + 64) else STAGE(0, k0 + 64)
    }
    if (buf == 0) COMPUTE(0) else COMPUTE(1)
    __syncthreads();               // drains next-tile gll; ds_reads retired
    buf ^= 1;
  }
#undef STAGE
#undef COMPUTE

  // epilogue: C/D layout col=lane&15, row=(lane>>4)*4+reg (r2-verified)
#pragma unroll
  for (int j = 0; j < 2; ++j) {
    int n = nBase + wc * 32 + j * 16 + rr;
    float bv = bias[n];
#pragma unroll
    for (int i = 0; i < 4; ++i) {
      int mrow = mBase + wr * 64 + i * 16 + q * 4;
#pragma unroll
      for (int r2 = 0; r2 < 4; ++r2) {
        int m = mrow + r2;
        if (m < Mtot) out[(size_t)m * N_DIM + n] = acc[i][j][r2] + bv;
      }
    }
  }
}

extern "C" void kernel_launch(void* const* d_in, const int* in_sizes, int n_in,
                              void* d_out, int out_size, void* d_ws, size_t ws_size,
                              hipStream_t stream) {
  const float* x  = (const float*)d_in[0];
  const float* iw = (const float*)d_in[1];
  const float* W  = (const float*)d_in[2];
  const float* b  = (const float*)d_in[3];
  int P = in_sizes[1];                        // 992
  int B = in_sizes[0] / (3 * 1024 * 1024);    // 8
  int E = in_sizes[3];                        // 768
  int T = out_size / (B * E);                 // 995
  int Mtot = B * T;                           // 7960
  int Mpad = (Mtot + 127) & ~127;             // 8064

  char* ws = (char*)d_ws;
  int* tokBase = (int*)ws;                              // 32 KB
  int* tokMask = (int*)(ws + 32768);                    // 32 KB
  unsigned short* Wb = (unsigned short*)(ws + 65536);   // 4.72 MB row-major
  unsigned short* Ab = (unsigned short*)(ws + 65536 + (size_t)E * K_DIM * 2);

  int w4 = E * K_DIM / 4;                     // 589824
  int NB_W = (w4 + 1023) / 1024;              // 576
  prep_kernel<<<NB_W + 1, 1024, 0, stream>>>(W, Wb, w4, iw, P, tokBase, tokMask, NB_W);

  dim3 gGrid(T, B);
  gather_kernel<<<gGrid, 256, 0, stream>>>(x, tokBase, tokMask, Ab);

  // pad rows [Mtot, Mpad) of Ab are never written; MFMA on poison is finite/NaN
  // garbage that only lands in acc values guarded off by m<Mtot in epilogue.

  dim3 grid((N_DIM / 64) * (Mpad / 128));     // 12*63 = 756 blocks, 1D for swizzle
  gemm_kernel<<<grid, 256, 0, stream>>>(Ab, Wb, b, (float*)d_out, Mtot);
}

// Round 2
// 236.155 us; speedup vs baseline: 1.0511x; 1.0170x over previous
//
#include <hip/hip_runtime.h>

// PatchEmbedding2 on MI355X — round 9.
// r8 post-mortem: occupancy fix worked (10->21%, FETCH 157->46MB) but gemm only
// 76->66us; MfmaUtil 23.6%, HBM 15% — no pipe saturated. Remaining stall: the
// per-iter __syncthreads drains vmcnt(0), exposing next-tile global_load_lds
// latency 48x. Fix (T4, counted vmcnt): STAGE(next); s_waitcnt vmcnt(6);
// s_barrier; COMPUTE(cur); s_waitcnt lgkmcnt(0); s_barrier. Next tile's 6 loads
// stay in flight across the barrier; lgkmcnt(0) (near-free, reads already
// consumed by MFMA) preserves the WAR guarantee vs next STAGE's LDS writes.
// Geometry unchanged from r8 (sync-structure edit isolated): BM128 BN64 BK64,
// dbuf 48KB, 3 blk/CU, 756 blocks, bijective XCD swizzle, swizzled staging.
// prep/gather: unchanged (r3/r4-verified).

typedef __attribute__((ext_vector_type(8))) short bf16x8;
typedef __attribute__((ext_vector_type(4))) float f32x4;

#define K_DIM 3072
#define N_DIM 768

__device__ __forceinline__ unsigned short f2bf(float f) {
  unsigned int u = __float_as_uint(f);
  u += 0x7fffu + ((u >> 16) & 1u);   // RNE
  return (unsigned short)(u >> 16);
}

__device__ __forceinline__ void gload16(const void* g, void* l) {
  __builtin_amdgcn_global_load_lds(
      (const __attribute__((address_space(1))) void*)g,
      (__attribute__((address_space(3))) void*)l, 16, 0, 0);
}

// ---------------- prep: wconv (row-major) + layout ----------------
__global__ __launch_bounds__(1024)
void prep_kernel(const float* __restrict__ W, unsigned short* __restrict__ Wb, int w4,
                 const float* __restrict__ iw, int P,
                 int* __restrict__ tokBase, int* __restrict__ tokMask, int NB_W) {
  int bid = blockIdx.x;
  int tid = threadIdx.x;
  if (bid < NB_W) {
    int idx = bid * 1024 + tid;
    if (idx < w4) {
      float4 f = *(const float4*)(W + (size_t)idx * 4);
      ushort4 o;
      o.x = f2bf(f.x); o.y = f2bf(f.y); o.z = f2bf(f.z); o.w = f2bf(f.w);
      *(ushort4*)(Wb + (size_t)idx * 4) = o;
    }
    return;
  }
  // ---- layout (single block, r2-verified) ----
  __shared__ double s_wsum[16];
  __shared__ double s_avg;
  __shared__ int s_cnt[1024];
  float v = (tid < P) ? iw[tid] : 0.0f;
  double d = (double)v;
#pragma unroll
  for (int off = 32; off > 0; off >>= 1) d += __shfl_down(d, off, 64);
  if ((tid & 63) == 0) s_wsum[tid >> 6] = d;
  __syncthreads();
  if (tid == 0) {
    double s = 0.0;
    for (int i = 0; i < 16; ++i) s += s_wsum[i];
    s_avg = s / (double)P;
  }
  __syncthreads();
  int cnt = 0, sz = 32;
  if (tid < P) {
    double val = 32.0 * pow(s_avg / (double)v, 0.05);
    if (val > 32.0) val = 32.0;
    sz = (val >= 24.0) ? 32 : (val >= 12.0) ? 16 : (val >= 6.0) ? 8 : 4;
    cnt = (sz < 32) ? (32 / sz) : 1;
  }
  s_cnt[tid] = cnt;
  __syncthreads();
  for (int dl = 1; dl < 1024; dl <<= 1) {
    int add = (tid >= dl) ? s_cnt[tid - dl] : 0;
    __syncthreads();
    s_cnt[tid] += add;
    __syncthreads();
  }
  if (tid < P) {
    int off = s_cnt[tid] - cnt;
    int ini_col = (tid * 32) & 1023;
    int ini_row = (tid * 32 * 32) >> 10;
    if (sz == 32) {
      tokBase[off] = ini_row * 1024 + ini_col;
      tokMask[off] = 31;
    } else {
      int ns = 32 / sz;
      for (int j = 0; j < ns; ++j) {
        int r = ini_row + (j * sz) / ns;
        int c = ini_col + ((j * sz) & 31);
        tokBase[off + j] = r * 1024 + c;
        tokMask[off + j] = sz - 1;
      }
    }
  }
}

// ---------------- gather: row-major Ab, one block per A row (r3/r4-verified) ---
__global__ __launch_bounds__(256)
void gather_kernel(const float* __restrict__ x,
                   const int* __restrict__ tokBase,
                   const int* __restrict__ tokMask,
                   unsigned short* __restrict__ Ab) {
  int t = blockIdx.x;
  int b = blockIdx.y;
  int T = gridDim.x;
  int m = b * T + t;
  int base = tokBase[t];
  int mask = tokMask[t];
  int sh = __popc(mask);
  const float* xb = x + (size_t)b * 3145728 + (size_t)base;
  unsigned short* arow = Ab + (size_t)m * K_DIM;
#pragma unroll
  for (int it = 0; it < 3; ++it) {
    int g = it * 256 + threadIdx.x;
    int p = g * 4;
    int c = p >> 10;
    int f = p & 1023;
    int h = (f >> sh) & mask;
    int w = f & mask;
    float4 fv = *(const float4*)(xb + (size_t)c * 1048576 + h * 1024 + w);
    ushort4 o;
    o.x = f2bf(fv.x); o.y = f2bf(fv.y); o.z = f2bf(fv.z); o.w = f2bf(fv.w);
    *(ushort4*)(arow + p) = o;
  }
}

// -------- gemm: 128x64 x BK64, dbuf LDS, counted-vmcnt 2-phase, 3 blk/CU -----
__global__ __launch_bounds__(256, 3)
void gemm_kernel(const unsigned short* __restrict__ A, const unsigned short* __restrict__ Wb,
                 const float* __restrict__ bias, float* __restrict__ out, int Mtot) {
  // per buf: A 128x64 halves (16 KB) at 0, B 64x64 halves (8 KB) at 8192.
  // row = 128 B = 8 chunks of 16 B; chunk c of row r stored at slot c^(r&7)
  // (swizzle applied in the GLOBAL src addr; gll LDS dst is linear lane*16).
  __shared__ unsigned short lds[2][12288];   // 48 KB total
  int tid = threadIdx.x;
  int lane = tid & 63;
  int wave = tid >> 6;
  int wr = wave >> 1, wc = wave & 1;         // wave tile: 64 rows x 32 cols

  // bijective XCD-chunked swizzle (m204): consecutive work ids (N-fastest,
  // sharing an A-panel) land on one XCD.
  int lin = blockIdx.x;
  int nwg = gridDim.x;                       // 756
  int q8 = nwg >> 3, r8 = nwg & 7;           // 94, 4
  int xcd = lin & 7, slot = lin >> 3;
  int wg = (xcd < r8) ? xcd * (q8 + 1) + slot
                      : r8 * (q8 + 1) + (xcd - r8) * q8 + slot;
  int mBase = (wg / 12) * 128;
  int nBase = (wg % 12) * 64;

  f32x4 acc[4][2] = {};

  // staging per buf: A = 4 gll insts/wave (rows wave*32+inst*8+(lane>>3)),
  // B = 2 gll insts/wave (rows wave*16+inst*8+(lane>>3)). Source chunk is
  // pre-swizzled: (lane&7)^(lane>>3)  (row&7 == lane>>3 for every inst).
  int lrow = lane >> 3;
  int schunk = (lane & 7) ^ lrow;
  const unsigned short* Ag = A + (size_t)(mBase + wave * 32 + lrow) * K_DIM + schunk * 8;
  const unsigned short* Bg = Wb + (size_t)(nBase + wave * 16 + lrow) * K_DIM + schunk * 8;
  unsigned short* Adst0 = &lds[0][(wave * 32) * 64] + lane * 8;          // +inst*512
  unsigned short* Bdst0 = &lds[0][8192 + (wave * 16) * 64] + lane * 8;   // +inst*512

#define STAGE(BUF, KOFF)                                                    \
  {                                                                         \
    _Pragma("unroll")                                                       \
    for (int inst = 0; inst < 4; ++inst)                                    \
      gload16(Ag + (size_t)(inst * 8) * K_DIM + (KOFF),                     \
              Adst0 + (size_t)(BUF) * 12288 + inst * 512);                  \
    _Pragma("unroll")                                                       \
    for (int inst = 0; inst < 2; ++inst)                                    \
      gload16(Bg + (size_t)(inst * 8) * K_DIM + (KOFF),                     \
              Bdst0 + (size_t)(BUF) * 12288 + inst * 512);                  \
  }

  int rr = lane & 15, q = lane >> 4;
  int r7 = rr & 7;

#define COMPUTE(BUF)                                                        \
  {                                                                         \
    const unsigned short* A_ = &lds[BUF][0];                                \
    const unsigned short* B_ = &lds[BUF][8192];                             \
    _Pragma("unroll")                                                       \
    for (int kh = 0; kh < 2; ++kh) {                                        \
      bf16x8 aF[4], bF[2];                                                  \
      _Pragma("unroll")                                                     \
      for (int i = 0; i < 4; ++i)                                           \
        aF[i] = *(const bf16x8*)&A_[(wr * 64 + i * 16 + rr) * 64 +          \
                                    ((kh * 4 + q) ^ r7) * 8];               \
      _Pragma("unroll")                                                     \
      for (int j = 0; j < 2; ++j)                                           \
        bF[j] = *(const bf16x8*)&B_[(wc * 32 + j * 16 + rr) * 64 +          \
                                    ((kh * 4 + q) ^ r7) * 8];               \
      _Pragma("unroll")                                                     \
      for (int i = 0; i < 4; ++i)                                           \
        _Pragma("unroll")                                                   \
        for (int j = 0; j < 2; ++j)                                         \
          acc[i][j] = __builtin_amdgcn_mfma_f32_16x16x32_bf16(aF[i], bF[j], \
                                                              acc[i][j], 0, 0, 0); \
    }                                                                       \
  }

  STAGE(0, 0)
  int buf = 0;
  // main loop: 47 iters, next tile's 6 gll stay in flight across the barrier.
  for (int k0 = 0; k0 < K_DIM - 64; k0 += 64) {
    if (buf == 0) STAGE(1, k0 + 64) else STAGE(0, k0 + 64)
    asm volatile("s_waitcnt vmcnt(6)" ::: "memory");   // own prev-tile 6 landed
    __builtin_amdgcn_s_barrier();                      // => all waves' landed
    if (buf == 0) COMPUTE(0) else COMPUTE(1)
    asm volatile("s_waitcnt lgkmcnt(0)" ::: "memory"); // ds_reads retired (WAR)
    __builtin_amdgcn_s_barrier();                      // before next STAGE hits buf
    buf ^= 1;
  }
  // peeled last iter: nothing left to stage, drain remaining 6.
  asm volatile("s_waitcnt vmcnt(0)" ::: "memory");
  __builtin_amdgcn_s_barrier();
  if (buf == 0) COMPUTE(0) else COMPUTE(1)
#undef STAGE
#undef COMPUTE

  // epilogue: C/D layout col=lane&15, row=(lane>>4)*4+reg (r2-verified)
#pragma unroll
  for (int j = 0; j < 2; ++j) {
    int n = nBase + wc * 32 + j * 16 + rr;
    float bv = bias[n];
#pragma unroll
    for (int i = 0; i < 4; ++i) {
      int mrow = mBase + wr * 64 + i * 16 + q * 4;
#pragma unroll
      for (int r2 = 0; r2 < 4; ++r2) {
        int m = mrow + r2;
        if (m < Mtot) out[(size_t)m * N_DIM + n] = acc[i][j][r2] + bv;
      }
    }
  }
}

extern "C" void kernel_launch(void* const* d_in, const int* in_sizes, int n_in,
                              void* d_out, int out_size, void* d_ws, size_t ws_size,
                              hipStream_t stream) {
  const float* x  = (const float*)d_in[0];
  const float* iw = (const float*)d_in[1];
  const float* W  = (const float*)d_in[2];
  const float* b  = (const float*)d_in[3];
  int P = in_sizes[1];                        // 992
  int B = in_sizes[0] / (3 * 1024 * 1024);    // 8
  int E = in_sizes[3];                        // 768
  int T = out_size / (B * E);                 // 995
  int Mtot = B * T;                           // 7960
  int Mpad = (Mtot + 127) & ~127;             // 8064

  char* ws = (char*)d_ws;
  int* tokBase = (int*)ws;                              // 32 KB
  int* tokMask = (int*)(ws + 32768);                    // 32 KB
  unsigned short* Wb = (unsigned short*)(ws + 65536);   // 4.72 MB row-major
  unsigned short* Ab = (unsigned short*)(ws + 65536 + (size_t)E * K_DIM * 2);

  int w4 = E * K_DIM / 4;                     // 589824
  int NB_W = (w4 + 1023) / 1024;              // 576
  prep_kernel<<<NB_W + 1, 1024, 0, stream>>>(W, Wb, w4, iw, P, tokBase, tokMask, NB_W);

  dim3 gGrid(T, B);
  gather_kernel<<<gGrid, 256, 0, stream>>>(x, tokBase, tokMask, Ab);

  // pad rows [Mtot, Mpad) of Ab are never written; MFMA on poison is finite/NaN
  // garbage that only lands in acc values guarded off by m<Mtot in epilogue.

  dim3 grid((N_DIM / 64) * (Mpad / 128));     // 12*63 = 756 blocks, 1D for swizzle
  gemm_kernel<<<grid, 256, 0, stream>>>(Ab, Wb, b, (float*)d_out, Mtot);
}

// Round 3
// 227.147 us; speedup vs baseline: 1.0928x; 1.0397x over previous
//
#include <hip/hip_runtime.h>

// PatchEmbedding2 on MI355X — round 10.
// r9 post-mortem: counted vmcnt gave only 66->63us -> NOT latency-bound;
// throughput model: per-CU LDS reads 6.9MB (~25us) + gll->LDS writes 3.45MB
// @~50B/cyc (~28us) ~= the 63us. Both terms are geometry: 64x32 wave tiles
// (0.046 B/FLOP reads) and BN=64 (A staged 12x, 870MB total).
// Fix: (BM,BN)=(192,128) -> 42x6 = 252 blocks = 1/CU (98% balance), 6 waves
// of 64x64 (reads 0.0305 B/FLOP), total staged 472MB (A 6x). 1 blk/CU is
// latency-fragile -> 3-buf LDS (120KB, m201 precedent) with depth-2 prefetch,
// counted vmcnt(20) (2 tiles always in flight). Staging on waves 0-3 only
// (10 gll each -> uniform vmcnt literal; waves 4-5 pass wait, sync at barrier).
// Swizzled 16B-chunk staging unchanged (row&7 == lane>>3 holds for 48/32-row
// slabs). prep/gather: unchanged (r3/r4-verified).

typedef __attribute__((ext_vector_type(8))) short bf16x8;
typedef __attribute__((ext_vector_type(4))) float f32x4;

#define K_DIM 3072
#define N_DIM 768
#define BM 192
#define BN 128

__device__ __forceinline__ unsigned short f2bf(float f) {
  unsigned int u = __float_as_uint(f);
  u += 0x7fffu + ((u >> 16) & 1u);   // RNE
  return (unsigned short)(u >> 16);
}

__device__ __forceinline__ void gload16(const void* g, void* l) {
  __builtin_amdgcn_global_load_lds(
      (const __attribute__((address_space(1))) void*)g,
      (__attribute__((address_space(3))) void*)l, 16, 0, 0);
}

// ---------------- prep: wconv (row-major) + layout ----------------
__global__ __launch_bounds__(1024)
void prep_kernel(const float* __restrict__ W, unsigned short* __restrict__ Wb, int w4,
                 const float* __restrict__ iw, int P,
                 int* __restrict__ tokBase, int* __restrict__ tokMask, int NB_W) {
  int bid = blockIdx.x;
  int tid = threadIdx.x;
  if (bid < NB_W) {
    int idx = bid * 1024 + tid;
    if (idx < w4) {
      float4 f = *(const float4*)(W + (size_t)idx * 4);
      ushort4 o;
      o.x = f2bf(f.x); o.y = f2bf(f.y); o.z = f2bf(f.z); o.w = f2bf(f.w);
      *(ushort4*)(Wb + (size_t)idx * 4) = o;
    }
    return;
  }
  // ---- layout (single block, r2-verified) ----
  __shared__ double s_wsum[16];
  __shared__ double s_avg;
  __shared__ int s_cnt[1024];
  float v = (tid < P) ? iw[tid] : 0.0f;
  double d = (double)v;
#pragma unroll
  for (int off = 32; off > 0; off >>= 1) d += __shfl_down(d, off, 64);
  if ((tid & 63) == 0) s_wsum[tid >> 6] = d;
  __syncthreads();
  if (tid == 0) {
    double s = 0.0;
    for (int i = 0; i < 16; ++i) s += s_wsum[i];
    s_avg = s / (double)P;
  }
  __syncthreads();
  int cnt = 0, sz = 32;
  if (tid < P) {
    double val = 32.0 * pow(s_avg / (double)v, 0.05);
    if (val > 32.0) val = 32.0;
    sz = (val >= 24.0) ? 32 : (val >= 12.0) ? 16 : (val >= 6.0) ? 8 : 4;
    cnt = (sz < 32) ? (32 / sz) : 1;
  }
  s_cnt[tid] = cnt;
  __syncthreads();
  for (int dl = 1; dl < 1024; dl <<= 1) {
    int add = (tid >= dl) ? s_cnt[tid - dl] : 0;
    __syncthreads();
    s_cnt[tid] += add;
    __syncthreads();
  }
  if (tid < P) {
    int off = s_cnt[tid] - cnt;
    int ini_col = (tid * 32) & 1023;
    int ini_row = (tid * 32 * 32) >> 10;
    if (sz == 32) {
      tokBase[off] = ini_row * 1024 + ini_col;
      tokMask[off] = 31;
    } else {
      int ns = 32 / sz;
      for (int j = 0; j < ns; ++j) {
        int r = ini_row + (j * sz) / ns;
        int c = ini_col + ((j * sz) & 31);
        tokBase[off + j] = r * 1024 + c;
        tokMask[off + j] = sz - 1;
      }
    }
  }
}

// ---------------- gather: row-major Ab, one block per A row (r3/r4-verified) ---
__global__ __launch_bounds__(256)
void gather_kernel(const float* __restrict__ x,
                   const int* __restrict__ tokBase,
                   const int* __restrict__ tokMask,
                   unsigned short* __restrict__ Ab) {
  int t = blockIdx.x;
  int b = blockIdx.y;
  int T = gridDim.x;
  int m = b * T + t;
  int base = tokBase[t];
  int mask = tokMask[t];
  int sh = __popc(mask);
  const float* xb = x + (size_t)b * 3145728 + (size_t)base;
  unsigned short* arow = Ab + (size_t)m * K_DIM;
#pragma unroll
  for (int it = 0; it < 3; ++it) {
    int g = it * 256 + threadIdx.x;
    int p = g * 4;
    int c = p >> 10;
    int f = p & 1023;
    int h = (f >> sh) & mask;
    int w = f & mask;
    float4 fv = *(const float4*)(xb + (size_t)c * 1048576 + h * 1024 + w);
    ushort4 o;
    o.x = f2bf(fv.x); o.y = f2bf(fv.y); o.z = f2bf(fv.z); o.w = f2bf(fv.w);
    *(ushort4*)(arow + p) = o;
  }
}

// ---- gemm: 192x128 x BK64, 3-buf LDS depth-2 prefetch, 1 blk/CU, 6 waves ----
__global__ __launch_bounds__(384)
void gemm_kernel(const unsigned short* __restrict__ A, const unsigned short* __restrict__ Wb,
                 const float* __restrict__ bias, float* __restrict__ out, int Mtot) {
  // per buf: A 192x64 (24 KB) at shorts[0], B 128x64 (16 KB) at shorts[12288].
  // row = 128 B = 8 chunks of 16 B; chunk c of row r stored at slot c^(r&7)
  // (swizzle applied in GLOBAL src addr; gll LDS dst is linear lane*16).
  __shared__ unsigned short lds[3][20480];   // 120 KB
  int tid = threadIdx.x;
  int lane = tid & 63;
  int wave = tid >> 6;                       // 0..5
  int wr = wave >> 1, wc = wave & 1;         // wave tile 64x64 at (wr*64, wc*64)

  // bijective XCD-chunked swizzle (m204), 252 blocks: consecutive work ids
  // (N-fastest, sharing an A-panel) land on one XCD.
  int lin = blockIdx.x;
  int nwg = gridDim.x;                       // 252
  int q8 = nwg >> 3, r8 = nwg & 7;           // 31, 4
  int xcd = lin & 7, slot = lin >> 3;
  int wg = (xcd < r8) ? xcd * (q8 + 1) + slot
                      : r8 * (q8 + 1) + (xcd - r8) * q8 + slot;
  int mBase = (wg / 6) * BM;
  int nBase = (wg % 6) * BN;

  f32x4 acc[4][4] = {};

  // staging (waves 0-3 only): A rows [w*48, w*48+48) = 6 insts, B rows
  // [w*32, w*32+32) = 4 insts; 10 gll/wave/stage. row&7 == lane>>3 always.
  int lrow = lane >> 3;
  int schunk = (lane & 7) ^ lrow;            // pre-swizzled source chunk
  const unsigned short* Ag = A + (size_t)(mBase + wave * 48 + lrow) * K_DIM + schunk * 8;
  const unsigned short* Bg = Wb + (size_t)(nBase + wave * 32 + lrow) * K_DIM + schunk * 8;
  unsigned short* Adst0 = &lds[0][(wave * 48) * 64] + lane * 8;           // +inst*512
  unsigned short* Bdst0 = &lds[0][12288 + (wave * 32) * 64] + lane * 8;   // +inst*512

#define STAGE(BUF, KOFF)                                                    \
  {                                                                         \
    if (wave < 4) {                                                         \
      _Pragma("unroll")                                                     \
      for (int inst = 0; inst < 6; ++inst)                                  \
        gload16(Ag + (size_t)(inst * 8) * K_DIM + (KOFF),                   \
                Adst0 + (size_t)(BUF) * 20480 + inst * 512);                \
      _Pragma("unroll")                                                     \
      for (int inst = 0; inst < 4; ++inst)                                  \
        gload16(Bg + (size_t)(inst * 8) * K_DIM + (KOFF),                   \
                Bdst0 + (size_t)(BUF) * 20480 + inst * 512);                \
    }                                                                       \
  }

  int rr = lane & 15, q = lane >> 4;
  int r7 = rr & 7;

#define COMPUTE(BUF)                                                        \
  {                                                                         \
    const unsigned short* A_ = &lds[BUF][0];                                \
    const unsigned short* B_ = &lds[BUF][12288];                            \
    _Pragma("unroll")                                                       \
    for (int kh = 0; kh < 2; ++kh) {                                        \
      bf16x8 aF[4], bF[4];                                                  \
      _Pragma("unroll")                                                     \
      for (int i = 0; i < 4; ++i)                                           \
        aF[i] = *(const bf16x8*)&A_[(wr * 64 + i * 16 + rr) * 64 +          \
                                    ((kh * 4 + q) ^ r7) * 8];               \
      _Pragma("unroll")                                                     \
      for (int j = 0; j < 4; ++j)                                           \
        bF[j] = *(const bf16x8*)&B_[(wc * 64 + j * 16 + rr) * 64 +          \
                                    ((kh * 4 + q) ^ r7) * 8];               \
      _Pragma("unroll")                                                     \
      for (int i = 0; i < 4; ++i)                                           \
        _Pragma("unroll")                                                   \
        for (int j = 0; j < 4; ++j)                                         \
          acc[i][j] = __builtin_amdgcn_mfma_f32_16x16x32_bf16(aF[i], bF[j], \
                                                              acc[i][j], 0, 0, 0); \
    }                                                                       \
  }

  // depth-2 pipeline over 48 K-tiles, buf = tile%3. In flight across each
  // barrier: 2 stages x 10 gll (waves 0-3) -> vmcnt(20) waits oldest stage.
  STAGE(0, 0)
  STAGE(1, 64)
  for (int t = 0; t < 15; ++t) {             // tiles 0..44
    int k = t * 192;
    STAGE(2, k + 128)
    asm volatile("s_waitcnt vmcnt(20)" ::: "memory");
    __builtin_amdgcn_s_barrier();
    COMPUTE(0)
    asm volatile("s_waitcnt lgkmcnt(0)" ::: "memory");
    __builtin_amdgcn_s_barrier();
    STAGE(0, k + 192)
    asm volatile("s_waitcnt vmcnt(20)" ::: "memory");
    __builtin_amdgcn_s_barrier();
    COMPUTE(1)
    asm volatile("s_waitcnt lgkmcnt(0)" ::: "memory");
    __builtin_amdgcn_s_barrier();
    STAGE(1, k + 256)
    asm volatile("s_waitcnt vmcnt(20)" ::: "memory");
    __builtin_amdgcn_s_barrier();
    COMPUTE(2)
    asm volatile("s_waitcnt lgkmcnt(0)" ::: "memory");
    __builtin_amdgcn_s_barrier();
  }
  // tile 45 (buf0): stages tile 47
  STAGE(2, 3008)
  asm volatile("s_waitcnt vmcnt(20)" ::: "memory");
  __builtin_amdgcn_s_barrier();
  COMPUTE(0)
  asm volatile("s_waitcnt lgkmcnt(0)" ::: "memory");
  __builtin_amdgcn_s_barrier();
  // tile 46 (buf1): only tile 47's 10 loads outstanding
  asm volatile("s_waitcnt vmcnt(10)" ::: "memory");
  __builtin_amdgcn_s_barrier();
  COMPUTE(1)
  asm volatile("s_waitcnt lgkmcnt(0)" ::: "memory");
  __builtin_amdgcn_s_barrier();
  // tile 47 (buf2): drain
  asm volatile("s_waitcnt vmcnt(0)" ::: "memory");
  __builtin_amdgcn_s_barrier();
  COMPUTE(2)
#undef STAGE
#undef COMPUTE

  // epilogue: C/D layout col=lane&15, row=(lane>>4)*4+reg (r2-verified)
#pragma unroll
  for (int j = 0; j < 4; ++j) {
    int n = nBase + wc * 64 + j * 16 + rr;
    float bv = bias[n];
#pragma unroll
    for (int i = 0; i < 4; ++i) {
      int mrow = mBase + wr * 64 + i * 16 + q * 4;
#pragma unroll
      for (int r2 = 0; r2 < 4; ++r2) {
        int m = mrow + r2;
        if (m < Mtot) out[(size_t)m * N_DIM + n] = acc[i][j][r2] + bv;
      }
    }
  }
}

extern "C" void kernel_launch(void* const* d_in, const int* in_sizes, int n_in,
                              void* d_out, int out_size, void* d_ws, size_t ws_size,
                              hipStream_t stream) {
  const float* x  = (const float*)d_in[0];
  const float* iw = (const float*)d_in[1];
  const float* W  = (const float*)d_in[2];
  const float* b  = (const float*)d_in[3];
  int P = in_sizes[1];                        // 992
  int B = in_sizes[0] / (3 * 1024 * 1024);    // 8
  int E = in_sizes[3];                        // 768
  int T = out_size / (B * E);                 // 995
  int Mtot = B * T;                           // 7960
  int mTiles = (Mtot + BM - 1) / BM;          // 42 (42*192 = 8064)

  char* ws = (char*)d_ws;
  int* tokBase = (int*)ws;                              // 32 KB
  int* tokMask = (int*)(ws + 32768);                    // 32 KB
  unsigned short* Wb = (unsigned short*)(ws + 65536);   // 4.72 MB row-major
  unsigned short* Ab = (unsigned short*)(ws + 65536 + (size_t)E * K_DIM * 2);

  int w4 = E * K_DIM / 4;                     // 589824
  int NB_W = (w4 + 1023) / 1024;              // 576
  prep_kernel<<<NB_W + 1, 1024, 0, stream>>>(W, Wb, w4, iw, P, tokBase, tokMask, NB_W);

  dim3 gGrid(T, B);
  gather_kernel<<<gGrid, 256, 0, stream>>>(x, tokBase, tokMask, Ab);

  // pad rows [Mtot, 8064) of Ab are never written; garbage affects only
  // output rows >= Mtot, guarded in the epilogue (matmul rows independent).

  dim3 grid((N_DIM / BN) * mTiles);           // 6*42 = 252 blocks, 1D for swizzle
  gemm_kernel<<<grid, 384, 0, stream>>>(Ab, Wb, b, (float*)d_out, Mtot);
}

// Round 4
// 224.792 us; speedup vs baseline: 1.1042x; 1.0105x over previous
//
#include <hip/hip_runtime.h>

// PatchEmbedding2 on MI355X — round 11.
// r10 post-mortem: traffic fix null (63->59us). Two causes: (1) 6 waves on 4
// SIMDs = {2,2,1,1} imbalance, ~25% matrix-pipe waste + no TLP; (2) we're AT
// the 2-phase structure ceiling (59us = 636 TF ~= m233's 607 TF ceiling) —
// stage+waitcnt+barrier overhead dominates regardless of tiles.
// Fix (T3+T5 on top of existing T2+T4): 8 waves (512thr, 2/SIMD balanced),
// wave tile 48x64 acc[3][4], uniform 5 gll/wave/tile (A:3,B:2), and per-K-tile
// 2-phase split: {7 ds_read || gll issue; barrier; lgkmcnt(0); sched_barrier;
// setprio(1) 12 MFMA setprio(0); barrier} x2, counted vmcnt(5) once/tile.
// Geometry kept from r10: BM192 BN128 BK64, 3-buf depth-2 (120KB), 252 blocks
// = 1/CU, bijective XCD swizzle, swizzled 16B-chunk staging.
// NOTE: harness fillBuffer (384MiB re-poison, ~60us @84% HBM) is a fixed
// floor outside our control; controllable = prep+gather+gemm ~= 100us.
// prep/gather: unchanged (r3/r4-verified).

typedef __attribute__((ext_vector_type(8))) short bf16x8;
typedef __attribute__((ext_vector_type(4))) float f32x4;

#define K_DIM 3072
#define N_DIM 768
#define BM 192
#define BN 128

__device__ __forceinline__ unsigned short f2bf(float f) {
  unsigned int u = __float_as_uint(f);
  u += 0x7fffu + ((u >> 16) & 1u);   // RNE
  return (unsigned short)(u >> 16);
}

__device__ __forceinline__ void gload16(const void* g, void* l) {
  __builtin_amdgcn_global_load_lds(
      (const __attribute__((address_space(1))) void*)g,
      (__attribute__((address_space(3))) void*)l, 16, 0, 0);
}

// ---------------- prep: wconv (row-major) + layout ----------------
__global__ __launch_bounds__(1024)
void prep_kernel(const float* __restrict__ W, unsigned short* __restrict__ Wb, int w4,
                 const float* __restrict__ iw, int P,
                 int* __restrict__ tokBase, int* __restrict__ tokMask, int NB_W) {
  int bid = blockIdx.x;
  int tid = threadIdx.x;
  if (bid < NB_W) {
    int idx = bid * 1024 + tid;
    if (idx < w4) {
      float4 f = *(const float4*)(W + (size_t)idx * 4);
      ushort4 o;
      o.x = f2bf(f.x); o.y = f2bf(f.y); o.z = f2bf(f.z); o.w = f2bf(f.w);
      *(ushort4*)(Wb + (size_t)idx * 4) = o;
    }
    return;
  }
  // ---- layout (single block, r2-verified) ----
  __shared__ double s_wsum[16];
  __shared__ double s_avg;
  __shared__ int s_cnt[1024];
  float v = (tid < P) ? iw[tid] : 0.0f;
  double d = (double)v;
#pragma unroll
  for (int off = 32; off > 0; off >>= 1) d += __shfl_down(d, off, 64);
  if ((tid & 63) == 0) s_wsum[tid >> 6] = d;
  __syncthreads();
  if (tid == 0) {
    double s = 0.0;
    for (int i = 0; i < 16; ++i) s += s_wsum[i];
    s_avg = s / (double)P;
  }
  __syncthreads();
  int cnt = 0, sz = 32;
  if (tid < P) {
    double val = 32.0 * pow(s_avg / (double)v, 0.05);
    if (val > 32.0) val = 32.0;
    sz = (val >= 24.0) ? 32 : (val >= 12.0) ? 16 : (val >= 6.0) ? 8 : 4;
    cnt = (sz < 32) ? (32 / sz) : 1;
  }
  s_cnt[tid] = cnt;
  __syncthreads();
  for (int dl = 1; dl < 1024; dl <<= 1) {
    int add = (tid >= dl) ? s_cnt[tid - dl] : 0;
    __syncthreads();
    s_cnt[tid] += add;
    __syncthreads();
  }
  if (tid < P) {
    int off = s_cnt[tid] - cnt;
    int ini_col = (tid * 32) & 1023;
    int ini_row = (tid * 32 * 32) >> 10;
    if (sz == 32) {
      tokBase[off] = ini_row * 1024 + ini_col;
      tokMask[off] = 31;
    } else {
      int ns = 32 / sz;
      for (int j = 0; j < ns; ++j) {
        int r = ini_row + (j * sz) / ns;
        int c = ini_col + ((j * sz) & 31);
        tokBase[off + j] = r * 1024 + c;
        tokMask[off + j] = sz - 1;
      }
    }
  }
}

// ---------------- gather: row-major Ab, one block per A row (r3/r4-verified) ---
__global__ __launch_bounds__(256)
void gather_kernel(const float* __restrict__ x,
                   const int* __restrict__ tokBase,
                   const int* __restrict__ tokMask,
                   unsigned short* __restrict__ Ab) {
  int t = blockIdx.x;
  int b = blockIdx.y;
  int T = gridDim.x;
  int m = b * T + t;
  int base = tokBase[t];
  int mask = tokMask[t];
  int sh = __popc(mask);
  const float* xb = x + (size_t)b * 3145728 + (size_t)base;
  unsigned short* arow = Ab + (size_t)m * K_DIM;
#pragma unroll
  for (int it = 0; it < 3; ++it) {
    int g = it * 256 + threadIdx.x;
    int p = g * 4;
    int c = p >> 10;
    int f = p & 1023;
    int h = (f >> sh) & mask;
    int w = f & mask;
    float4 fv = *(const float4*)(xb + (size_t)c * 1048576 + h * 1024 + w);
    ushort4 o;
    o.x = f2bf(fv.x); o.y = f2bf(fv.y); o.z = f2bf(fv.z); o.w = f2bf(fv.w);
    *(ushort4*)(arow + p) = o;
  }
}

// -- gemm: 192x128 x BK64, 8 waves, 3-buf depth-2, 2-phase/tile + setprio -----
__global__ __launch_bounds__(512)
void gemm_kernel(const unsigned short* __restrict__ A, const unsigned short* __restrict__ Wb,
                 const float* __restrict__ bias, float* __restrict__ out, int Mtot) {
  // per buf: A 192x64 (24 KB) shorts [0,12288), B 128x64 (16 KB) [12288,20480).
  // row = 128 B = 8 chunks of 16 B; chunk c of row r stored at slot c^(r&7)
  // (swizzle applied in GLOBAL src addr; gll LDS dst is linear lane*16).
  __shared__ unsigned short lds[3][20480];   // 120 KB
  int tid = threadIdx.x;
  int lane = tid & 63;
  int wave = tid >> 6;                       // 0..7
  int wrM = wave >> 1, wrN = wave & 1;       // wave tile 48x64 at (wrM*48, wrN*64)

  // bijective XCD-chunked swizzle (m204), 252 blocks.
  int lin = blockIdx.x;
  int nwg = gridDim.x;                       // 252
  int q8 = nwg >> 3, r8 = nwg & 7;           // 31, 4
  int xcd = lin & 7, slot = lin >> 3;
  int wg = (xcd < r8) ? xcd * (q8 + 1) + slot
                      : r8 * (q8 + 1) + (xcd - r8) * q8 + slot;
  int mBase = (wg / 6) * BM;
  int nBase = (wg % 6) * BN;

  f32x4 acc[3][4] = {};

  // staging: uniform 5 gll/wave/tile. A: rows wave*24 + inst*8 + lrow (3 insts)
  // B: rows wave*16 + inst*8 + lrow (2 insts). 24,16,48,64 all ≡0 mod 8 so
  // row&7 == lane>>3 == lrow always; source chunk pre-swizzled (lane&7)^lrow.
  int lrow = lane >> 3;
  int schunk = (lane & 7) ^ lrow;
  const unsigned short* Ag = A + (size_t)(mBase + wave * 24 + lrow) * K_DIM + schunk * 8;
  const unsigned short* Bg = Wb + (size_t)(nBase + wave * 16 + lrow) * K_DIM + schunk * 8;
  unsigned short* Adst0 = &lds[0][(wave * 24) * 64] + lane * 8;           // +inst*512
  unsigned short* Bdst0 = &lds[0][12288 + (wave * 16) * 64] + lane * 8;   // +inst*512

#define STAGE_A(BUF, KOFF)                                                  \
    _Pragma("unroll")                                                       \
    for (int inst = 0; inst < 3; ++inst)                                    \
      gload16(Ag + (size_t)(inst * 8) * K_DIM + (KOFF),                     \
              Adst0 + (size_t)(BUF) * 20480 + inst * 512);

#define STAGE_B(BUF, KOFF)                                                  \
    _Pragma("unroll")                                                       \
    for (int inst = 0; inst < 2; ++inst)                                    \
      gload16(Bg + (size_t)(inst * 8) * K_DIM + (KOFF),                     \
              Bdst0 + (size_t)(BUF) * 20480 + inst * 512);

  int rr = lane & 15, q = lane >> 4;
  int r7 = rr & 7;

  // one phase: ds_read this phase's frags, issue share of next-next-tile
  // stage, optional counted vmcnt, barrier, lgkmcnt(0)+sched_barrier (rule
  // 18), prio-wrapped 12 MFMA, barrier.
#define PH(BUF, KH, STG, WAITC)                                             \
  {                                                                         \
    bf16x8 aF[3], bF[4];                                                    \
    _Pragma("unroll")                                                       \
    for (int i = 0; i < 3; ++i)                                             \
      aF[i] = *(const bf16x8*)&lds[BUF][(wrM * 48 + i * 16 + rr) * 64 +     \
                                        (((KH) * 4 + q) ^ r7) * 8];         \
    _Pragma("unroll")                                                       \
    for (int j = 0; j < 4; ++j)                                             \
      bF[j] = *(const bf16x8*)&lds[BUF][12288 +                             \
                                        (wrN * 64 + j * 16 + rr) * 64 +     \
                                        (((KH) * 4 + q) ^ r7) * 8];         \
    STG                                                                     \
    WAITC                                                                   \
    __builtin_amdgcn_s_barrier();                                           \
    asm volatile("s_waitcnt lgkmcnt(0)" ::: "memory");                      \
    __builtin_amdgcn_sched_barrier(0);                                      \
    __builtin_amdgcn_s_setprio(1);                                          \
    _Pragma("unroll")                                                       \
    for (int i = 0; i < 3; ++i)                                             \
      _Pragma("unroll")                                                     \
      for (int j = 0; j < 4; ++j)                                           \
        acc[i][j] = __builtin_amdgcn_mfma_f32_16x16x32_bf16(aF[i], bF[j],   \
                                                            acc[i][j], 0, 0, 0); \
    __builtin_amdgcn_s_setprio(0);                                          \
    __builtin_amdgcn_s_barrier();                                           \
  }

#define VM5 asm volatile("s_waitcnt vmcnt(5)" ::: "memory");
#define VM0 asm volatile("s_waitcnt vmcnt(0)" ::: "memory");
#define NOP

  // iter t (buf t%3): phase0 stages A of tile t+2, phase1 stages B of t+2
  // then waits vmcnt(5) => tile t+1's 5 landed before next iter's ds_reads.
#define ITER(BUF, SBUF, KOFF)                                               \
  PH(BUF, 0, STAGE_A(SBUF, KOFF), NOP)                                      \
  PH(BUF, 1, STAGE_B(SBUF, KOFF), VM5)

  // prologue: stage tiles 0,1; wait tile 0 landed (10 outstanding -> vmcnt(5))
  STAGE_A(0, 0) STAGE_B(0, 0)
  STAGE_A(1, 64) STAGE_B(1, 64)
  VM5
  __builtin_amdgcn_s_barrier();

  for (int g = 0; g < 15; ++g) {             // tiles 0..44
    int k = g * 192;
    ITER(0, 2, k + 128)
    ITER(1, 0, k + 192)
    ITER(2, 1, k + 256)
  }
  // tile 45 (buf0): stages tile 47 into buf2
  ITER(0, 2, 3008)
  // tile 46 (buf1): nothing to stage; need tile 47 landed at end
  PH(1, 0, NOP, NOP)
  PH(1, 1, NOP, VM0)
  // tile 47 (buf2): drained
  PH(2, 0, NOP, NOP)
  PH(2, 1, NOP, NOP)
#undef ITER
#undef PH
#undef STAGE_A
#undef STAGE_B
#undef VM5
#undef VM0
#undef NOP

  // epilogue: C/D layout col=lane&15, row=(lane>>4)*4+reg (r2-verified)
#pragma unroll
  for (int j = 0; j < 4; ++j) {
    int n = nBase + wrN * 64 + j * 16 + rr;
    float bv = bias[n];
#pragma unroll
    for (int i = 0; i < 3; ++i) {
      int mrow = mBase + wrM * 48 + i * 16 + q * 4;
#pragma unroll
      for (int r2 = 0; r2 < 4; ++r2) {
        int m = mrow + r2;
        if (m < Mtot) out[(size_t)m * N_DIM + n] = acc[i][j][r2] + bv;
      }
    }
  }
}

extern "C" void kernel_launch(void* const* d_in, const int* in_sizes, int n_in,
                              void* d_out, int out_size, void* d_ws, size_t ws_size,
                              hipStream_t stream) {
  const float* x  = (const float*)d_in[0];
  const float* iw = (const float*)d_in[1];
  const float* W  = (const float*)d_in[2];
  const float* b  = (const float*)d_in[3];
  int P = in_sizes[1];                        // 992
  int B = in_sizes[0] / (3 * 1024 * 1024);    // 8
  int E = in_sizes[3];                        // 768
  int T = out_size / (B * E);                 // 995
  int Mtot = B * T;                           // 7960
  int mTiles = (Mtot + BM - 1) / BM;          // 42 (42*192 = 8064)

  char* ws = (char*)d_ws;
  int* tokBase = (int*)ws;                              // 32 KB
  int* tokMask = (int*)(ws + 32768);                    // 32 KB
  unsigned short* Wb = (unsigned short*)(ws + 65536);   // 4.72 MB row-major
  unsigned short* Ab = (unsigned short*)(ws + 65536 + (size_t)E * K_DIM * 2);

  int w4 = E * K_DIM / 4;                     // 589824
  int NB_W = (w4 + 1023) / 1024;              // 576
  prep_kernel<<<NB_W + 1, 1024, 0, stream>>>(W, Wb, w4, iw, P, tokBase, tokMask, NB_W);

  dim3 gGrid(T, B);
  gather_kernel<<<gGrid, 256, 0, stream>>>(x, tokBase, tokMask, Ab);

  // pad rows [Mtot, 8064) of Ab are never written; garbage affects only
  // output rows >= Mtot, guarded in the epilogue (matmul rows independent).

  dim3 grid((N_DIM / BN) * mTiles);           // 6*42 = 252 blocks, 1D for swizzle
  gemm_kernel<<<grid, 512, 0, stream>>>(Ab, Wb, b, (float*)d_out, Mtot);
}